// Round 14
// baseline (200.654 us; speedup 1.0000x reference)
//
#include <hip/hip_runtime.h>
#include <math.h>

#define BATCH 2
#define CH    192
#define NPTS  8192
#define KNN   9

#define NT     64      // rows per normalize block
#define TLIST  8       // per-lane candidate list depth
#define NT32   256     // 32-wide point tiles per batch
#define KS     12      // 192 / 16
#define CSPLIT 16      // cand-space splits (phase 1)
#define NITER  (NT32 / CSPLIT)   // 16
#define NCANDP 256     // packed candidates per query (16 cs * 2 h * 8)
#define P2ROWS 4       // phase-2 rows per block (1 per wave)
#define NSEL   16      // candidates exactly re-ranked per row

typedef __attribute__((ext_vector_type(8)))  short  bf16x8;
typedef __attribute__((ext_vector_type(8)))  unsigned short u16x8;
typedef __attribute__((ext_vector_type(16))) float  f32x16;

static __device__ __forceinline__ unsigned short f2bf(float f) {
    unsigned u = __float_as_uint(f);
    u += 0x7fffu + ((u >> 16) & 1u);          // round-to-nearest-even
    return (unsigned short)(u >> 16);
}
static __device__ __forceinline__ bf16x8 negbf(bf16x8 v) {
    bf16x8 r;
    #pragma unroll
    for (int e = 0; e < 8; ++e) r[e] = (short)(v[e] ^ (short)0x8000);
    return r;
}
static __device__ __forceinline__ unsigned umax2(unsigned a, unsigned b) {
    return a > b ? a : b;
}
static __device__ __forceinline__ unsigned umin2(unsigned a, unsigned b) {
    return a < b ? a : b;
}

// ---------------------------------------------------------------------------
// Kernel A: norms + layouts (unchanged — passing since R13).
//  pk [B][tile32(256)][ks(12)][lane(64)*8] bf16
//     element: point = tile32*32 + (lane&31), k = ks*16 + (lane>>5)*8 + e
//  x_rm [B][N][C] f32 raw; rdnd/ssd f64 per point.
// ---------------------------------------------------------------------------
__global__ __launch_bounds__(256) void knn_normalize(
    const float* __restrict__ x,
    unsigned short* __restrict__ pk, float* __restrict__ x_rm,
    double* __restrict__ rdnd, double* __restrict__ ssd)
{
    __shared__ float  tile[CH][NT + 1];
    __shared__ double rdn_sh[NT];

    const int b   = blockIdx.x >> 7;
    const int rb  = blockIdx.x & 127;
    const int n0  = rb << 6;
    const int tid = threadIdx.x;
    const float* xb = x + (size_t)b * CH * NPTS;

    #pragma unroll
    for (int i = 0; i < (CH * NT) / 256; ++i) {
        int flat = tid + i * 256;
        int c = flat >> 6, j = flat & 63;
        tile[c][j] = xb[(size_t)c * NPTS + n0 + j];
    }
    __syncthreads();

    // 4 threads per point: quarter q covers dims q*48..q*48+47
    {
        const int j = tid >> 2, q = tid & 3;
        double ss = 0.0;
        #pragma unroll 8
        for (int c = 0; c < 48; ++c) {
            double v = (double)tile[q * 48 + c][j];
            ss = fma(v, v, ss);
        }
        ss += __shfl_xor(ss, 1, 64);
        ss += __shfl_xor(ss, 2, 64);
        if (q == 0) {
            double dn = sqrt(ss);
            if (dn < 1e-12) dn = 1e-12;
            double rdn = 1.0 / dn;
            rdn_sh[j] = rdn;
            rdnd[b * NPTS + n0 + j] = rdn;
            ssd [b * NPTS + n0 + j] = ss;
        }
    }
    __syncthreads();

    // packed MFMA-frag bf16 (2 tile32s * 12 ksteps = 24 frags/block)
    #pragma unroll
    for (int i = 0; i < 6; ++i) {
        int pid  = tid + i * 256;
        int frag = pid >> 6;              // 0..23
        int lane = pid & 63;
        int tl   = frag / KS;             // 0..1
        int ks   = frag - tl * KS;        // 0..11
        int rl   = (tl << 5) + (lane & 31);          // local point 0..63
        int kb   = (ks << 4) + ((lane >> 5) << 3);   // k base
        double rdn = rdn_sh[rl];
        u16x8 hv;
        #pragma unroll
        for (int e = 0; e < 8; ++e) {
            float v = (float)((double)tile[kb + e][rl] * rdn);
            hv[e] = f2bf(v);
        }
        size_t base = ((size_t)((b * NT32 + (rb << 1) + tl) * KS + ks)) * 512
                      + ((size_t)lane << 3);
        *(u16x8*)(pk + base) = hv;
    }

    #pragma unroll
    for (int i = 0; i < (CH * NT) / 256; ++i) {
        int flat = tid + i * 256;
        int j = flat / CH, c = flat - j * CH;
        x_rm[(size_t)(b * NPTS + n0 + j) * CH + c] = tile[c][j];
    }
}

// ---------------------------------------------------------------------------
// Phase 1 v11: R13 structure (32x32x16 swapped-operand MFMA, lane owns one
// query + one depth-8 list) with BRANCHLESS selection:
//   q = umin(p, wmax); lst[t] = (lst[t]==wmax) ? q : lst[t]; rebuild wmax.
// If p >= wmax: q == wmax -> all slots no-op. If p < wmax: exactly one slot
// equals wmax (payloads unique) and takes p. ~25 VALU/key, zero divergence
// (R13 measured ~52/key with the per-key branch).
// ---------------------------------------------------------------------------
__global__ __attribute__((amdgpu_flat_work_group_size(256, 256),
                          amdgpu_waves_per_eu(4, 4)))
void knn_phase1(
    const unsigned short* __restrict__ pk,
    unsigned* __restrict__ cand_p)
{
    __shared__ unsigned short ldsB[2][KS * 512];   // 2 x 12288 B

    const int bid  = blockIdx.x;          // 2048
    const int b    = bid >> 10;
    const int r10  = bid & 1023;
    const int qb   = r10 >> 4;            // query block 0..63 (128 queries)
    const int cs   = r10 & 15;            // cand split 0..15 (512 cands)
    const int tid  = threadIdx.x;
    const int wave = tid >> 6;            // 0..3
    const int lane = tid & 63;
    const unsigned short* pkb = pk + (size_t)b * (NT32 * KS * 512);

    // query fragments (B operand), negated for acc = 4 - inner
    const int qt = qb * 4 + wave;         // query tile32 0..255
    bf16x8 qf[KS];
    #pragma unroll
    for (int ks = 0; ks < KS; ++ks) {
        const unsigned short* p = pkb + ((size_t)(qt * KS + ks)) * 512 + (lane << 3);
        qf[ks] = negbf(*(const bf16x8*)p);
    }

    // single depth-8 list; sentinels above all real keys (real < 0x40D00000)
    unsigned lst[TLIST];
    unsigned wmax;
    #pragma unroll
    for (int t = 0; t < TLIST; ++t) lst[t] = 0xFFFFFF00u | t;
    wmax = 0xFFFFFF00u | (TLIST - 1);

    // prologue stage of cand tile cs*16 (12288 B = 3 x 256 x 16B)
    {
        const char* g = (const char*)(pkb + (size_t)(cs * NITER) * (KS * 512));
        #pragma unroll
        for (int k = 0; k < 3; ++k) {
            int off = (k * 256 + tid) * 16;
            __builtin_amdgcn_global_load_lds(
                (const __attribute__((address_space(1))) unsigned int*)(g + off),
                (__attribute__((address_space(3))) unsigned int*)((char*)&ldsB[0][0] + off),
                16, 0, 0);
        }
    }
    __syncthreads();

    for (int it = 0; it < NITER; ++it) {
        const int cur = it & 1;
        if (it + 1 < NITER) {
            const char* g = (const char*)(pkb + (size_t)(cs * NITER + it + 1) * (KS * 512));
            #pragma unroll
            for (int k = 0; k < 3; ++k) {
                int off = (k * 256 + tid) * 16;
                __builtin_amdgcn_global_load_lds(
                    (const __attribute__((address_space(1))) unsigned int*)(g + off),
                    (__attribute__((address_space(3))) unsigned int*)((char*)&ldsB[cur ^ 1][0] + off),
                    16, 0, 0);
            }
        }

        f32x16 acc;
        #pragma unroll
        for (int r = 0; r < 16; ++r) acc[r] = 4.f;

        #pragma unroll
        for (int ks = 0; ks < KS; ++ks) {
            bf16x8 cf = *(const bf16x8*)&ldsB[cur][(ks << 9) + (lane << 3)];
            acc = __builtin_amdgcn_mfma_f32_32x32x16_bf16(cf, qf[ks], acc, 0, 0, 0);
        }

        // branchless selection: key = 4 - inner (positive -> uint order)
        // packed = (bits & ~0xFF) | (it<<4) | reg
        const unsigned pb = (unsigned)(it << 4);
        #pragma unroll
        for (int r = 0; r < 16; ++r) {
            unsigned p = (__float_as_uint(acc[r]) & 0xFFFFFF00u) | pb | (unsigned)r;
            const unsigned wm = wmax;
            const unsigned q = umin2(p, wm);
            #pragma unroll
            for (int t = 0; t < TLIST; ++t)
                lst[t] = (lst[t] == wm) ? q : lst[t];
            unsigned m0 = umax2(lst[0], lst[1]);
            unsigned m1 = umax2(lst[2], lst[3]);
            unsigned m2 = umax2(lst[4], lst[5]);
            unsigned m3 = umax2(lst[6], lst[7]);
            wmax = umax2(umax2(m0, m1), umax2(m2, m3));
        }
        __syncthreads();
    }

    // write: [B*N query][cs(16)][h(2)][8]
    const int query = (qt << 5) + (lane & 31);
    const int h     = lane >> 5;
    unsigned* dst = cand_p + ((size_t)(b * NPTS + query) << 8) + (cs << 4) + (h << 3);
    uint4 w0 = make_uint4(lst[0], lst[1], lst[2], lst[3]);
    uint4 w1 = make_uint4(lst[4], lst[5], lst[6], lst[7]);
    *(uint4*)dst       = w0;
    *(uint4*)(dst + 4) = w1;
}

// ---------------------------------------------------------------------------
// Phase 2 (unchanged from R13 — passing): 1 query per wave, 4 per block.
//  (a) per-lane 4 packed cands (uint4), sort4, NSEL(16)-round wave-min
//      extraction; col reconstructed from (cs,h) list identity + payload.
//  (b) f64 re-rank (16 cands): lane=(cand,quarter), float4 gathers, 2-shfl
//  (c) lane-0 serial 9-of-16 by (f64 key, idx)
// ---------------------------------------------------------------------------
__global__ __launch_bounds__(256) void knn_phase2(
    const float* __restrict__ x_rm,
    const double* __restrict__ rdnd, const double* __restrict__ ssd,
    const unsigned* __restrict__ cand_p,
    int* __restrict__ out)
{
    __shared__ double xc[P2ROWS][CH];     // 6144 B
    __shared__ int    sel[P2ROWS][16];
    __shared__ double dks[P2ROWS][16];

    const int bi   = blockIdx.x;          // 4096
    const int b    = bi >> 11;
    const int r0   = (bi & 2047) << 2;
    const int tid  = threadIdx.x;
    const int wave = tid >> 6;
    const int lane = tid & 63;
    const int bN   = b * NPTS;

    for (int i = tid; i < P2ROWS * CH; i += 256) {
        int r = i / CH, c = i - r * CH;
        xc[r][c] = (double)x_rm[(size_t)(bN + r0 + r) * CH + c] * rdnd[bN + r0 + r];
    }
    __syncthreads();

    const int row = r0 + wave;

    // (a) lane's 4 slots: flat f = lane*4+u; cs = f>>4, h = (f>>3)&1, t = f&7
    unsigned long long qq[4];
    {
        uint4 pv = *(const uint4*)(cand_p + ((size_t)(bN + row) << 8) + (lane << 2));
        unsigned pk4[4] = {pv.x, pv.y, pv.z, pv.w};
        #pragma unroll
        for (int u = 0; u < 4; ++u) {
            int f = (lane << 2) + u;
            int cs = f >> 4, h = (f >> 3) & 1;
            unsigned pkv = pk4[u];
            int r = (int)(pkv & 15u), ct = (int)((pkv >> 4) & 15u);
            int rowc = (r & 3) + ((r >> 2) << 3) + (h << 2);
            int col  = (cs << 9) + (ct << 5) + rowc;
            qq[u] = ((unsigned long long)pkv << 32) | (unsigned)col;
        }
        // sort4 ascending (5 CE)
        unsigned long long t;
        #define CE(a, b) if (qq[b] < qq[a]) { t = qq[a]; qq[a] = qq[b]; qq[b] = t; }
        CE(0,1) CE(2,3) CE(0,2) CE(1,3) CE(1,2)
        #undef CE
    }

    // NSEL extraction rounds of wave-wide u64 min; lane r captures round r
    unsigned long long my_sel = 0;
    #pragma unroll
    for (int round = 0; round < NSEL; ++round) {
        unsigned long long m = qq[0];
        #pragma unroll
        for (int off = 1; off < 64; off <<= 1) {
            unsigned long long o = __shfl_xor(m, off, 64);
            m = (o < m) ? o : m;
        }
        if (qq[0] == m) {                 // exactly one lane (u64 unique via col)
            qq[0] = qq[1]; qq[1] = qq[2]; qq[2] = qq[3];
            qq[3] = 0xFFFFFFFFFFFFFFFFull;
        }
        if (lane == round) my_sel = m;
    }
    if (lane < NSEL) sel[wave][lane] = (int)((unsigned)my_sel & 0x3FFFu);
    __builtin_amdgcn_wave_barrier();

    // (b) exact f64 keys: lane = (cand c, quarter qd)
    {
        const int c = lane & 15, qd = lane >> 4;
        const int m = sel[wave][c];
        const double rdm = rdnd[bN + m];
        const float* xr = x_rm + (size_t)(bN + m) * CH + qd * 48;
        const double* xcp = &xc[wave][qd * 48];
        double s0 = 0.0, s1 = 0.0, s2 = 0.0, s3 = 0.0;
        #pragma unroll
        for (int j = 0; j < 12; ++j) {
            float4 v = *(const float4*)(xr + (j << 2));
            s0 = fma((double)v.x * rdm, xcp[(j << 2) + 0], s0);
            s1 = fma((double)v.y * rdm, xcp[(j << 2) + 1], s1);
            s2 = fma((double)v.z * rdm, xcp[(j << 2) + 2], s2);
            s3 = fma((double)v.w * rdm, xcp[(j << 2) + 3], s3);
        }
        double dot = (s0 + s1) + (s2 + s3);
        dot += __shfl_xor(dot, 16, 64);
        dot += __shfl_xor(dot, 32, 64);
        if (qd == 0) dks[wave][c] = fma(-2.0, dot, ssd[bN + m] * rdm * rdm);
    }
    __builtin_amdgcn_wave_barrier();

    // (c) 9 smallest of 16 by (key, idx) — serial on lane 0 of each wave
    if (lane == 0) {
        const int n = row;
        unsigned used = 0;
        for (int k = 0; k < KNN; ++k) {
            double bd = INFINITY; int bm = 0x7fffffff; int bp = 0;
            #pragma unroll
            for (int s = 0; s < 16; ++s) {
                if (!((used >> s) & 1u)) {
                    double d = dks[wave][s]; int m = sel[wave][s];
                    if (d < bd || (d == bd && m < bm)) { bd = d; bm = m; bp = s; }
                }
            }
            used |= (1u << bp);
            out[(size_t)(bN + n) * KNN + k] = bm;
            out[(size_t)BATCH * NPTS * KNN + (size_t)(bN + n) * KNN + k] = n;
        }
    }
}

// ---------------------------------------------------------------------------
extern "C" void kernel_launch(void* const* d_in, const int* in_sizes, int n_in,
                              void* d_out, int out_size, void* d_ws, size_t ws_size,
                              hipStream_t stream)
{
    const float* x = (const float*)d_in[0];
    int* out = (int*)d_out;

    char* ws = (char*)d_ws;
    const size_t sz_pk  = (size_t)BATCH * NT32 * KS * 512 * sizeof(unsigned short); // 6.29 MB
    const size_t sz_xrm = (size_t)BATCH * NPTS * CH * sizeof(float);                // 12.58 MB
    const size_t sz_rdn = (size_t)BATCH * NPTS * sizeof(double);
    const size_t sz_ss  = sz_rdn;

    unsigned short* pk = (unsigned short*)(ws);
    float*  x_rm   = (float*) (ws + sz_pk);
    double* rdnd   = (double*)(ws + sz_pk + sz_xrm);
    double* ssd    = (double*)(ws + sz_pk + sz_xrm + sz_rdn);
    unsigned* cand_p = (unsigned*)(ws + sz_pk + sz_xrm + sz_rdn + sz_ss);           // 16.8 MB

    knn_normalize<<<BATCH * (NPTS / NT), 256, 0, stream>>>(x, pk, x_rm, rdnd, ssd);
    knn_phase1  <<<BATCH * 64 * CSPLIT, 256, 0, stream>>>(pk, cand_p);
    knn_phase2  <<<BATCH * (NPTS / P2ROWS), 256, 0, stream>>>(x_rm, rdnd, ssd, cand_p, out);
}

// Round 15
// 183.762 us; speedup vs baseline: 1.0919x; 1.0919x over previous
//
#include <hip/hip_runtime.h>
#include <math.h>

#define BATCH 2
#define CH    192
#define NPTS  8192
#define KNN   9

#define NT     64      // rows per normalize block
#define TLIST  8       // per-lane candidate list depth
#define NT32   256     // 32-wide point tiles per batch
#define KS     12      // 192 / 16
#define CSPLIT 16      // cand-space splits (phase 1)
#define NITER  (NT32 / CSPLIT)   // 16
#define NCANDP 256     // packed candidates per query (16 cs * 2 h * 8)
#define P2ROWS 4       // phase-2 rows per block (1 per wave)
#define NSEL   16      // candidates exactly re-ranked per row

typedef __attribute__((ext_vector_type(8)))  short  bf16x8;
typedef __attribute__((ext_vector_type(8)))  unsigned short u16x8;
typedef __attribute__((ext_vector_type(16))) float  f32x16;

static __device__ __forceinline__ unsigned short f2bf(float f) {
    unsigned u = __float_as_uint(f);
    u += 0x7fffu + ((u >> 16) & 1u);          // round-to-nearest-even
    return (unsigned short)(u >> 16);
}
static __device__ __forceinline__ bf16x8 negbf(bf16x8 v) {
    bf16x8 r;
    #pragma unroll
    for (int e = 0; e < 8; ++e) r[e] = (short)(v[e] ^ (short)0x8000);
    return r;
}
static __device__ __forceinline__ unsigned umax2(unsigned a, unsigned b) {
    return a > b ? a : b;
}
static __device__ __forceinline__ unsigned umin2(unsigned a, unsigned b) {
    return a < b ? a : b;
}

// ---------------------------------------------------------------------------
// Kernel A: norms + layouts (unchanged — passing since R13).
//  pk [B][tile32(256)][ks(12)][lane(64)*8] bf16
//     element: point = tile32*32 + (lane&31), k = ks*16 + (lane>>5)*8 + e
//  x_rm [B][N][C] f32 raw; rdnd/ssd f64 per point.
// ---------------------------------------------------------------------------
__global__ __launch_bounds__(256) void knn_normalize(
    const float* __restrict__ x,
    unsigned short* __restrict__ pk, float* __restrict__ x_rm,
    double* __restrict__ rdnd, double* __restrict__ ssd)
{
    __shared__ float  tile[CH][NT + 1];
    __shared__ double rdn_sh[NT];

    const int b   = blockIdx.x >> 7;
    const int rb  = blockIdx.x & 127;
    const int n0  = rb << 6;
    const int tid = threadIdx.x;
    const float* xb = x + (size_t)b * CH * NPTS;

    #pragma unroll
    for (int i = 0; i < (CH * NT) / 256; ++i) {
        int flat = tid + i * 256;
        int c = flat >> 6, j = flat & 63;
        tile[c][j] = xb[(size_t)c * NPTS + n0 + j];
    }
    __syncthreads();

    // 4 threads per point: quarter q covers dims q*48..q*48+47
    {
        const int j = tid >> 2, q = tid & 3;
        double ss = 0.0;
        #pragma unroll 8
        for (int c = 0; c < 48; ++c) {
            double v = (double)tile[q * 48 + c][j];
            ss = fma(v, v, ss);
        }
        ss += __shfl_xor(ss, 1, 64);
        ss += __shfl_xor(ss, 2, 64);
        if (q == 0) {
            double dn = sqrt(ss);
            if (dn < 1e-12) dn = 1e-12;
            double rdn = 1.0 / dn;
            rdn_sh[j] = rdn;
            rdnd[b * NPTS + n0 + j] = rdn;
            ssd [b * NPTS + n0 + j] = ss;
        }
    }
    __syncthreads();

    // packed MFMA-frag bf16 (2 tile32s * 12 ksteps = 24 frags/block)
    #pragma unroll
    for (int i = 0; i < 6; ++i) {
        int pid  = tid + i * 256;
        int frag = pid >> 6;              // 0..23
        int lane = pid & 63;
        int tl   = frag / KS;             // 0..1
        int ks   = frag - tl * KS;        // 0..11
        int rl   = (tl << 5) + (lane & 31);          // local point 0..63
        int kb   = (ks << 4) + ((lane >> 5) << 3);   // k base
        double rdn = rdn_sh[rl];
        u16x8 hv;
        #pragma unroll
        for (int e = 0; e < 8; ++e) {
            float v = (float)((double)tile[kb + e][rl] * rdn);
            hv[e] = f2bf(v);
        }
        size_t base = ((size_t)((b * NT32 + (rb << 1) + tl) * KS + ks)) * 512
                      + ((size_t)lane << 3);
        *(u16x8*)(pk + base) = hv;
    }

    #pragma unroll
    for (int i = 0; i < (CH * NT) / 256; ++i) {
        int flat = tid + i * 256;
        int j = flat / CH, c = flat - j * CH;
        x_rm[(size_t)(b * NPTS + n0 + j) * CH + c] = tile[c][j];
    }
}

// ---------------------------------------------------------------------------
// Phase 1 v12: R13 structure (32x32x16 swapped-operand MFMA, lane owns one
// query) with SORTED-LADDER selection: lst[0..7] kept sorted ascending;
// insert = 8x {min,max} ladder, 16 VOP2 per key, NO wmax, NO compare
// results, NO divergence. Worse-than-all keys fall off the end naturally.
// Per-iter "+v" pins coax the list into arch VGPRs (kill accvgpr traffic).
// ---------------------------------------------------------------------------
__global__ __attribute__((amdgpu_flat_work_group_size(256, 256),
                          amdgpu_waves_per_eu(4, 4)))
void knn_phase1(
    const unsigned short* __restrict__ pk,
    unsigned* __restrict__ cand_p)
{
    __shared__ unsigned short ldsB[2][KS * 512];   // 2 x 12288 B

    const int bid  = blockIdx.x;          // 2048
    const int b    = bid >> 10;
    const int r10  = bid & 1023;
    const int qb   = r10 >> 4;            // query block 0..63 (128 queries)
    const int cs   = r10 & 15;            // cand split 0..15 (512 cands)
    const int tid  = threadIdx.x;
    const int wave = tid >> 6;            // 0..3
    const int lane = tid & 63;
    const unsigned short* pkb = pk + (size_t)b * (NT32 * KS * 512);

    // query fragments (B operand), negated for acc = 4 - inner
    const int qt = qb * 4 + wave;         // query tile32 0..255
    bf16x8 qf[KS];
    #pragma unroll
    for (int ks = 0; ks < KS; ++ks) {
        const unsigned short* p = pkb + ((size_t)(qt * KS + ks)) * 512 + (lane << 3);
        qf[ks] = negbf(*(const bf16x8*)p);
    }

    // sorted-ascending list; sentinels above all real keys (real < 0x40D00000)
    unsigned lst[TLIST];
    #pragma unroll
    for (int t = 0; t < TLIST; ++t) lst[t] = 0xFFFFFF00u | t;

    // prologue stage of cand tile cs*16 (12288 B = 3 x 256 x 16B)
    {
        const char* g = (const char*)(pkb + (size_t)(cs * NITER) * (KS * 512));
        #pragma unroll
        for (int k = 0; k < 3; ++k) {
            int off = (k * 256 + tid) * 16;
            __builtin_amdgcn_global_load_lds(
                (const __attribute__((address_space(1))) unsigned int*)(g + off),
                (__attribute__((address_space(3))) unsigned int*)((char*)&ldsB[0][0] + off),
                16, 0, 0);
        }
    }
    __syncthreads();

    for (int it = 0; it < NITER; ++it) {
        const int cur = it & 1;
        if (it + 1 < NITER) {
            const char* g = (const char*)(pkb + (size_t)(cs * NITER + it + 1) * (KS * 512));
            #pragma unroll
            for (int k = 0; k < 3; ++k) {
                int off = (k * 256 + tid) * 16;
                __builtin_amdgcn_global_load_lds(
                    (const __attribute__((address_space(1))) unsigned int*)(g + off),
                    (__attribute__((address_space(3))) unsigned int*)((char*)&ldsB[cur ^ 1][0] + off),
                    16, 0, 0);
            }
        }

        f32x16 acc;
        #pragma unroll
        for (int r = 0; r < 16; ++r) acc[r] = 4.f;

        #pragma unroll
        for (int ks = 0; ks < KS; ++ks) {
            bf16x8 cf = *(const bf16x8*)&ldsB[cur][(ks << 9) + (lane << 3)];
            acc = __builtin_amdgcn_mfma_f32_32x32x16_bf16(cf, qf[ks], acc, 0, 0, 0);
        }

        // sorted-ladder selection: key = 4 - inner (positive -> uint order)
        // packed = (bits & ~0xFF) | (it<<4) | reg ; payload makes keys unique
        const unsigned pb = (unsigned)(it << 4);
        #pragma unroll
        for (int r = 0; r < 16; ++r) {
            unsigned hi = (__float_as_uint(acc[r]) & 0xFFFFFF00u) | pb | (unsigned)r;
            #pragma unroll
            for (int t = 0; t < TLIST; ++t) {
                unsigned lo = umin2(lst[t], hi);
                hi = umax2(lst[t], hi);
                lst[t] = lo;
            }
        }
        // coax list into arch VGPRs at the loop back-edge
        asm volatile("" : "+v"(lst[0]), "+v"(lst[1]), "+v"(lst[2]), "+v"(lst[3]),
                          "+v"(lst[4]), "+v"(lst[5]), "+v"(lst[6]), "+v"(lst[7]));
        __syncthreads();
    }

    // write: [B*N query][cs(16)][h(2)][8]  (list is sorted ascending)
    const int query = (qt << 5) + (lane & 31);
    const int h     = lane >> 5;
    unsigned* dst = cand_p + ((size_t)(b * NPTS + query) << 8) + (cs << 4) + (h << 3);
    uint4 w0 = make_uint4(lst[0], lst[1], lst[2], lst[3]);
    uint4 w1 = make_uint4(lst[4], lst[5], lst[6], lst[7]);
    *(uint4*)dst       = w0;
    *(uint4*)(dst + 4) = w1;
}

// ---------------------------------------------------------------------------
// Phase 2 (unchanged from R13 — passing): 1 query per wave, 4 per block.
//  (a) per-lane 4 packed cands (uint4), sort4, NSEL(16)-round wave-min
//      extraction; col reconstructed from (cs,h) list identity + payload.
//  (b) f64 re-rank (16 cands): lane=(cand,quarter), float4 gathers, 2-shfl
//  (c) lane-0 serial 9-of-16 by (f64 key, idx)
// ---------------------------------------------------------------------------
__global__ __launch_bounds__(256) void knn_phase2(
    const float* __restrict__ x_rm,
    const double* __restrict__ rdnd, const double* __restrict__ ssd,
    const unsigned* __restrict__ cand_p,
    int* __restrict__ out)
{
    __shared__ double xc[P2ROWS][CH];     // 6144 B
    __shared__ int    sel[P2ROWS][16];
    __shared__ double dks[P2ROWS][16];

    const int bi   = blockIdx.x;          // 4096
    const int b    = bi >> 11;
    const int r0   = (bi & 2047) << 2;
    const int tid  = threadIdx.x;
    const int wave = tid >> 6;
    const int lane = tid & 63;
    const int bN   = b * NPTS;

    for (int i = tid; i < P2ROWS * CH; i += 256) {
        int r = i / CH, c = i - r * CH;
        xc[r][c] = (double)x_rm[(size_t)(bN + r0 + r) * CH + c] * rdnd[bN + r0 + r];
    }
    __syncthreads();

    const int row = r0 + wave;

    // (a) lane's 4 slots: flat f = lane*4+u; cs = f>>4, h = (f>>3)&1, t = f&7
    unsigned long long qq[4];
    {
        uint4 pv = *(const uint4*)(cand_p + ((size_t)(bN + row) << 8) + (lane << 2));
        unsigned pk4[4] = {pv.x, pv.y, pv.z, pv.w};
        #pragma unroll
        for (int u = 0; u < 4; ++u) {
            int f = (lane << 2) + u;
            int cs = f >> 4, h = (f >> 3) & 1;
            unsigned pkv = pk4[u];
            int r = (int)(pkv & 15u), ct = (int)((pkv >> 4) & 15u);
            int rowc = (r & 3) + ((r >> 2) << 3) + (h << 2);
            int col  = (cs << 9) + (ct << 5) + rowc;
            qq[u] = ((unsigned long long)pkv << 32) | (unsigned)col;
        }
        // sort4 ascending (5 CE)
        unsigned long long t;
        #define CE(a, b) if (qq[b] < qq[a]) { t = qq[a]; qq[a] = qq[b]; qq[b] = t; }
        CE(0,1) CE(2,3) CE(0,2) CE(1,3) CE(1,2)
        #undef CE
    }

    // NSEL extraction rounds of wave-wide u64 min; lane r captures round r
    unsigned long long my_sel = 0;
    #pragma unroll
    for (int round = 0; round < NSEL; ++round) {
        unsigned long long m = qq[0];
        #pragma unroll
        for (int off = 1; off < 64; off <<= 1) {
            unsigned long long o = __shfl_xor(m, off, 64);
            m = (o < m) ? o : m;
        }
        if (qq[0] == m) {                 // exactly one lane (u64 unique via col)
            qq[0] = qq[1]; qq[1] = qq[2]; qq[2] = qq[3];
            qq[3] = 0xFFFFFFFFFFFFFFFFull;
        }
        if (lane == round) my_sel = m;
    }
    if (lane < NSEL) sel[wave][lane] = (int)((unsigned)my_sel & 0x3FFFu);
    __builtin_amdgcn_wave_barrier();

    // (b) exact f64 keys: lane = (cand c, quarter qd)
    {
        const int c = lane & 15, qd = lane >> 4;
        const int m = sel[wave][c];
        const double rdm = rdnd[bN + m];
        const float* xr = x_rm + (size_t)(bN + m) * CH + qd * 48;
        const double* xcp = &xc[wave][qd * 48];
        double s0 = 0.0, s1 = 0.0, s2 = 0.0, s3 = 0.0;
        #pragma unroll
        for (int j = 0; j < 12; ++j) {
            float4 v = *(const float4*)(xr + (j << 2));
            s0 = fma((double)v.x * rdm, xcp[(j << 2) + 0], s0);
            s1 = fma((double)v.y * rdm, xcp[(j << 2) + 1], s1);
            s2 = fma((double)v.z * rdm, xcp[(j << 2) + 2], s2);
            s3 = fma((double)v.w * rdm, xcp[(j << 2) + 3], s3);
        }
        double dot = (s0 + s1) + (s2 + s3);
        dot += __shfl_xor(dot, 16, 64);
        dot += __shfl_xor(dot, 32, 64);
        if (qd == 0) dks[wave][c] = fma(-2.0, dot, ssd[bN + m] * rdm * rdm);
    }
    __builtin_amdgcn_wave_barrier();

    // (c) 9 smallest of 16 by (key, idx) — serial on lane 0 of each wave
    if (lane == 0) {
        const int n = row;
        unsigned used = 0;
        for (int k = 0; k < KNN; ++k) {
            double bd = INFINITY; int bm = 0x7fffffff; int bp = 0;
            #pragma unroll
            for (int s = 0; s < 16; ++s) {
                if (!((used >> s) & 1u)) {
                    double d = dks[wave][s]; int m = sel[wave][s];
                    if (d < bd || (d == bd && m < bm)) { bd = d; bm = m; bp = s; }
                }
            }
            used |= (1u << bp);
            out[(size_t)(bN + n) * KNN + k] = bm;
            out[(size_t)BATCH * NPTS * KNN + (size_t)(bN + n) * KNN + k] = n;
        }
    }
}

// ---------------------------------------------------------------------------
extern "C" void kernel_launch(void* const* d_in, const int* in_sizes, int n_in,
                              void* d_out, int out_size, void* d_ws, size_t ws_size,
                              hipStream_t stream)
{
    const float* x = (const float*)d_in[0];
    int* out = (int*)d_out;

    char* ws = (char*)d_ws;
    const size_t sz_pk  = (size_t)BATCH * NT32 * KS * 512 * sizeof(unsigned short); // 6.29 MB
    const size_t sz_xrm = (size_t)BATCH * NPTS * CH * sizeof(float);                // 12.58 MB
    const size_t sz_rdn = (size_t)BATCH * NPTS * sizeof(double);
    const size_t sz_ss  = sz_rdn;

    unsigned short* pk = (unsigned short*)(ws);
    float*  x_rm   = (float*) (ws + sz_pk);
    double* rdnd   = (double*)(ws + sz_pk + sz_xrm);
    double* ssd    = (double*)(ws + sz_pk + sz_xrm + sz_rdn);
    unsigned* cand_p = (unsigned*)(ws + sz_pk + sz_xrm + sz_rdn + sz_ss);           // 16.8 MB

    knn_normalize<<<BATCH * (NPTS / NT), 256, 0, stream>>>(x, pk, x_rm, rdnd, ssd);
    knn_phase1  <<<BATCH * 64 * CSPLIT, 256, 0, stream>>>(pk, cand_p);
    knn_phase2  <<<BATCH * (NPTS / P2ROWS), 256, 0, stream>>>(x_rm, rdnd, ssd, cand_p, out);
}

// Round 16
// 161.305 us; speedup vs baseline: 1.2439x; 1.1392x over previous
//
#include <hip/hip_runtime.h>
#include <math.h>

#define BATCH 2
#define CH    192
#define NPTS  8192
#define KNN   9

#define NT     64      // rows per normalize block
#define TLIST  8       // per-lane candidate list depth
#define NT32   256     // 32-wide point tiles per batch
#define KS     12      // 192 / 16
#define CSPLIT 16      // cand-space splits (phase 1)
#define NITER  (NT32 / CSPLIT)   // 16
#define NCANDP 256     // packed candidates per query (16 cs * 2 h * 8)
#define P2ROWS 4       // phase-2 rows per block (1 per wave)
#define NSEL   12      // candidates exactly re-ranked per row

typedef __attribute__((ext_vector_type(8)))  short  bf16x8;
typedef __attribute__((ext_vector_type(8)))  unsigned short u16x8;
typedef __attribute__((ext_vector_type(16))) float  f32x16;

static __device__ __forceinline__ unsigned short f2bf(float f) {
    unsigned u = __float_as_uint(f);
    u += 0x7fffu + ((u >> 16) & 1u);          // round-to-nearest-even
    return (unsigned short)(u >> 16);
}
static __device__ __forceinline__ bf16x8 negbf(bf16x8 v) {
    bf16x8 r;
    #pragma unroll
    for (int e = 0; e < 8; ++e) r[e] = (short)(v[e] ^ (short)0x8000);
    return r;
}
static __device__ __forceinline__ unsigned umax2(unsigned a, unsigned b) {
    return a > b ? a : b;
}
static __device__ __forceinline__ unsigned umin2(unsigned a, unsigned b) {
    return a < b ? a : b;
}

// ---------------------------------------------------------------------------
// Kernel A: norms + layouts (unchanged — passing since R13).
//  pk [B][tile32(256)][ks(12)][lane(64)*8] bf16
//     element: point = tile32*32 + (lane&31), k = ks*16 + (lane>>5)*8 + e
//  x_rm [B][N][C] f32 raw; rdnd/ssd f64 per point.
// ---------------------------------------------------------------------------
__global__ __launch_bounds__(256) void knn_normalize(
    const float* __restrict__ x,
    unsigned short* __restrict__ pk, float* __restrict__ x_rm,
    double* __restrict__ rdnd, double* __restrict__ ssd)
{
    __shared__ float  tile[CH][NT + 1];
    __shared__ double rdn_sh[NT];

    const int b   = blockIdx.x >> 7;
    const int rb  = blockIdx.x & 127;
    const int n0  = rb << 6;
    const int tid = threadIdx.x;
    const float* xb = x + (size_t)b * CH * NPTS;

    #pragma unroll
    for (int i = 0; i < (CH * NT) / 256; ++i) {
        int flat = tid + i * 256;
        int c = flat >> 6, j = flat & 63;
        tile[c][j] = xb[(size_t)c * NPTS + n0 + j];
    }
    __syncthreads();

    // 4 threads per point: quarter q covers dims q*48..q*48+47
    {
        const int j = tid >> 2, q = tid & 3;
        double ss = 0.0;
        #pragma unroll 8
        for (int c = 0; c < 48; ++c) {
            double v = (double)tile[q * 48 + c][j];
            ss = fma(v, v, ss);
        }
        ss += __shfl_xor(ss, 1, 64);
        ss += __shfl_xor(ss, 2, 64);
        if (q == 0) {
            double dn = sqrt(ss);
            if (dn < 1e-12) dn = 1e-12;
            double rdn = 1.0 / dn;
            rdn_sh[j] = rdn;
            rdnd[b * NPTS + n0 + j] = rdn;
            ssd [b * NPTS + n0 + j] = ss;
        }
    }
    __syncthreads();

    // packed MFMA-frag bf16 (2 tile32s * 12 ksteps = 24 frags/block)
    #pragma unroll
    for (int i = 0; i < 6; ++i) {
        int pid  = tid + i * 256;
        int frag = pid >> 6;              // 0..23
        int lane = pid & 63;
        int tl   = frag / KS;             // 0..1
        int ks   = frag - tl * KS;        // 0..11
        int rl   = (tl << 5) + (lane & 31);          // local point 0..63
        int kb   = (ks << 4) + ((lane >> 5) << 3);   // k base
        double rdn = rdn_sh[rl];
        u16x8 hv;
        #pragma unroll
        for (int e = 0; e < 8; ++e) {
            float v = (float)((double)tile[kb + e][rl] * rdn);
            hv[e] = f2bf(v);
        }
        size_t base = ((size_t)((b * NT32 + (rb << 1) + tl) * KS + ks)) * 512
                      + ((size_t)lane << 3);
        *(u16x8*)(pk + base) = hv;
    }

    #pragma unroll
    for (int i = 0; i < (CH * NT) / 256; ++i) {
        int flat = tid + i * 256;
        int j = flat / CH, c = flat - j * CH;
        x_rm[(size_t)(b * NPTS + n0 + j) * CH + c] = tile[c][j];
    }
}

// ---------------------------------------------------------------------------
// Phase 1 v13: NO LDS, NO barriers. Cand fragments stream global->reg
// (pk is L2-resident 6.3 MB; all 4 waves/blk + 4 blks/CU read the same
// lines -> L1 serves re-reads; 16 waves/CU TLP hides L2 latency). Deletes
// per iter: 3 global_load_lds + 12 ds_read + 2 syncthreads + vmcnt drains.
// Selection: sorted-ladder (R15, proven). Lane owns 1 query, 1 depth-8 list.
// ---------------------------------------------------------------------------
__global__ __attribute__((amdgpu_flat_work_group_size(256, 256),
                          amdgpu_waves_per_eu(4, 4)))
void knn_phase1(
    const unsigned short* __restrict__ pk,
    unsigned* __restrict__ cand_p)
{
    const int bid  = blockIdx.x;          // 2048
    const int b    = bid >> 10;
    const int r10  = bid & 1023;
    const int qb   = r10 >> 4;            // query block 0..63 (128 queries)
    const int cs   = r10 & 15;            // cand split 0..15 (512 cands)
    const int tid  = threadIdx.x;
    const int wave = tid >> 6;            // 0..3
    const int lane = tid & 63;
    const unsigned short* pkb = pk + (size_t)b * (NT32 * KS * 512);

    // query fragments (B operand), negated for acc = 4 - inner
    const int qt = qb * 4 + wave;         // query tile32 0..255
    bf16x8 qf[KS];
    #pragma unroll
    for (int ks = 0; ks < KS; ++ks) {
        const unsigned short* p = pkb + ((size_t)(qt * KS + ks)) * 512 + (lane << 3);
        qf[ks] = negbf(*(const bf16x8*)p);
    }
    #pragma unroll
    for (int ks = 0; ks < KS; ++ks)
        asm volatile("" : "+a"(qf[ks]));   // MFMA-only operand: AGPR class

    // sorted-ascending list; sentinels above all real keys (real < 0x40D00000)
    unsigned lst[TLIST];
    #pragma unroll
    for (int t = 0; t < TLIST; ++t) lst[t] = 0xFFFFFF00u | t;

    const unsigned short* gbase = pkb + (size_t)(cs * NITER) * (KS * 512) + (lane << 3);

    for (int it = 0; it < NITER; ++it) {
        const unsigned short* gt = gbase + (size_t)it * (KS * 512);

        f32x16 acc;
        #pragma unroll
        for (int r = 0; r < 16; ++r) acc[r] = 4.f;

        #pragma unroll
        for (int ks = 0; ks < KS; ++ks) {
            bf16x8 cf = *(const bf16x8*)(gt + (ks << 9));
            acc = __builtin_amdgcn_mfma_f32_32x32x16_bf16(cf, qf[ks], acc, 0, 0, 0);
        }

        // sorted-ladder selection: key = 4 - inner (positive -> uint order)
        // packed = (bits & ~0xFF) | (it<<4) | reg ; payload makes keys unique
        const unsigned pb = (unsigned)(it << 4);
        #pragma unroll
        for (int r = 0; r < 16; ++r) {
            unsigned hi = (__float_as_uint(acc[r]) & 0xFFFFFF00u) | pb | (unsigned)r;
            #pragma unroll
            for (int t = 0; t < TLIST; ++t) {
                unsigned lo = umin2(lst[t], hi);
                hi = umax2(lst[t], hi);
                lst[t] = lo;
            }
        }
        // keep list in arch VGPRs at the loop back-edge
        asm volatile("" : "+v"(lst[0]), "+v"(lst[1]), "+v"(lst[2]), "+v"(lst[3]),
                          "+v"(lst[4]), "+v"(lst[5]), "+v"(lst[6]), "+v"(lst[7]));
    }

    // write: [B*N query][cs(16)][h(2)][8]  (list is sorted ascending)
    const int query = (qt << 5) + (lane & 31);
    const int h     = lane >> 5;
    unsigned* dst = cand_p + ((size_t)(b * NPTS + query) << 8) + (cs << 4) + (h << 3);
    uint4 w0 = make_uint4(lst[0], lst[1], lst[2], lst[3]);
    uint4 w1 = make_uint4(lst[4], lst[5], lst[6], lst[7]);
    *(uint4*)dst       = w0;
    *(uint4*)(dst + 4) = w1;
}

// ---------------------------------------------------------------------------
// Phase 2: 1 query per wave, 4 per block, 4096 blocks. NSEL=12.
//  (a) per-lane 4 packed cands (uint4), sort4, 12-round wave-min extraction
//      (each lane holds 4 -> top-12 needs <=4/lane: exact)
//  (b) f64 re-rank (12 cands): lane=(cand,quarter), float4 gathers, 2-shfl
//  (c) lane-0 serial 9-of-12 by (f64 key, idx)
// ---------------------------------------------------------------------------
__global__ __launch_bounds__(256) void knn_phase2(
    const float* __restrict__ x_rm,
    const double* __restrict__ rdnd, const double* __restrict__ ssd,
    const unsigned* __restrict__ cand_p,
    int* __restrict__ out)
{
    __shared__ double xc[P2ROWS][CH];     // 6144 B
    __shared__ int    sel[P2ROWS][16];
    __shared__ double dks[P2ROWS][16];

    const int bi   = blockIdx.x;          // 4096
    const int b    = bi >> 11;
    const int r0   = (bi & 2047) << 2;
    const int tid  = threadIdx.x;
    const int wave = tid >> 6;
    const int lane = tid & 63;
    const int bN   = b * NPTS;

    for (int i = tid; i < P2ROWS * CH; i += 256) {
        int r = i / CH, c = i - r * CH;
        xc[r][c] = (double)x_rm[(size_t)(bN + r0 + r) * CH + c] * rdnd[bN + r0 + r];
    }
    __syncthreads();

    const int row = r0 + wave;

    // (a) lane's 4 slots: flat f = lane*4+u; cs = f>>4, h = (f>>3)&1, t = f&7
    unsigned long long qq[4];
    {
        uint4 pv = *(const uint4*)(cand_p + ((size_t)(bN + row) << 8) + (lane << 2));
        unsigned pk4[4] = {pv.x, pv.y, pv.z, pv.w};
        #pragma unroll
        for (int u = 0; u < 4; ++u) {
            int f = (lane << 2) + u;
            int cs = f >> 4, h = (f >> 3) & 1;
            unsigned pkv = pk4[u];
            int r = (int)(pkv & 15u), ct = (int)((pkv >> 4) & 15u);
            int rowc = (r & 3) + ((r >> 2) << 3) + (h << 2);
            int col  = (cs << 9) + (ct << 5) + rowc;
            qq[u] = ((unsigned long long)pkv << 32) | (unsigned)col;
        }
        // sort4 ascending (5 CE)
        unsigned long long t;
        #define CE(a, b) if (qq[b] < qq[a]) { t = qq[a]; qq[a] = qq[b]; qq[b] = t; }
        CE(0,1) CE(2,3) CE(0,2) CE(1,3) CE(1,2)
        #undef CE
    }

    // NSEL extraction rounds of wave-wide u64 min; lane r captures round r
    unsigned long long my_sel = 0;
    #pragma unroll
    for (int round = 0; round < NSEL; ++round) {
        unsigned long long m = qq[0];
        #pragma unroll
        for (int off = 1; off < 64; off <<= 1) {
            unsigned long long o = __shfl_xor(m, off, 64);
            m = (o < m) ? o : m;
        }
        if (qq[0] == m) {                 // exactly one lane (u64 unique via col)
            qq[0] = qq[1]; qq[1] = qq[2]; qq[2] = qq[3];
            qq[3] = 0xFFFFFFFFFFFFFFFFull;
        }
        if (lane == round) my_sel = m;
    }
    if (lane < NSEL) sel[wave][lane] = (int)((unsigned)my_sel & 0x3FFFu);
    __builtin_amdgcn_wave_barrier();

    // (b) exact f64 keys: lane = (cand c, quarter qd), c < NSEL active
    {
        const int c = lane & 15, qd = lane >> 4;
        if (c < NSEL) {
            const int m = sel[wave][c];
            const double rdm = rdnd[bN + m];
            const float* xr = x_rm + (size_t)(bN + m) * CH + qd * 48;
            const double* xcp = &xc[wave][qd * 48];
            double s0 = 0.0, s1 = 0.0, s2 = 0.0, s3 = 0.0;
            #pragma unroll
            for (int j = 0; j < 12; ++j) {
                float4 v = *(const float4*)(xr + (j << 2));
                s0 = fma((double)v.x * rdm, xcp[(j << 2) + 0], s0);
                s1 = fma((double)v.y * rdm, xcp[(j << 2) + 1], s1);
                s2 = fma((double)v.z * rdm, xcp[(j << 2) + 2], s2);
                s3 = fma((double)v.w * rdm, xcp[(j << 2) + 3], s3);
            }
            double dot = (s0 + s1) + (s2 + s3);
            dot += __shfl_xor(dot, 16, 64);
            dot += __shfl_xor(dot, 32, 64);
            if (qd == 0) dks[wave][c] = fma(-2.0, dot, ssd[bN + m] * rdm * rdm);
        } else {
            double dot = 0.0;             // keep shuffles wave-uniform
            dot += __shfl_xor(dot, 16, 64);
            dot += __shfl_xor(dot, 32, 64);
        }
    }
    __builtin_amdgcn_wave_barrier();

    // (c) 9 smallest of NSEL by (key, idx) — serial on lane 0 of each wave
    if (lane == 0) {
        const int n = row;
        unsigned used = 0;
        for (int k = 0; k < KNN; ++k) {
            double bd = INFINITY; int bm = 0x7fffffff; int bp = 0;
            #pragma unroll
            for (int s = 0; s < NSEL; ++s) {
                if (!((used >> s) & 1u)) {
                    double d = dks[wave][s]; int m = sel[wave][s];
                    if (d < bd || (d == bd && m < bm)) { bd = d; bm = m; bp = s; }
                }
            }
            used |= (1u << bp);
            out[(size_t)(bN + n) * KNN + k] = bm;
            out[(size_t)BATCH * NPTS * KNN + (size_t)(bN + n) * KNN + k] = n;
        }
    }
}

// ---------------------------------------------------------------------------
extern "C" void kernel_launch(void* const* d_in, const int* in_sizes, int n_in,
                              void* d_out, int out_size, void* d_ws, size_t ws_size,
                              hipStream_t stream)
{
    const float* x = (const float*)d_in[0];
    int* out = (int*)d_out;

    char* ws = (char*)d_ws;
    const size_t sz_pk  = (size_t)BATCH * NT32 * KS * 512 * sizeof(unsigned short); // 6.29 MB
    const size_t sz_xrm = (size_t)BATCH * NPTS * CH * sizeof(float);                // 12.58 MB
    const size_t sz_rdn = (size_t)BATCH * NPTS * sizeof(double);
    const size_t sz_ss  = sz_rdn;

    unsigned short* pk = (unsigned short*)(ws);
    float*  x_rm   = (float*) (ws + sz_pk);
    double* rdnd   = (double*)(ws + sz_pk + sz_xrm);
    double* ssd    = (double*)(ws + sz_pk + sz_xrm + sz_rdn);
    unsigned* cand_p = (unsigned*)(ws + sz_pk + sz_xrm + sz_rdn + sz_ss);           // 16.8 MB

    knn_normalize<<<BATCH * (NPTS / NT), 256, 0, stream>>>(x, pk, x_rm, rdnd, ssd);
    knn_phase1  <<<BATCH * 64 * CSPLIT, 256, 0, stream>>>(pk, cand_p);
    knn_phase2  <<<BATCH * (NPTS / P2ROWS), 256, 0, stream>>>(x_rm, rdnd, ssd, cand_p, out);
}

// Round 17
// 160.721 us; speedup vs baseline: 1.2485x; 1.0036x over previous
//
#include <hip/hip_runtime.h>
#include <math.h>

#define BATCH 2
#define CH    192
#define NPTS  8192
#define KNN   9

#define NT     64      // rows per normalize block
#define TLIST  8       // per-lane candidate list depth
#define NT32   256     // 32-wide point tiles per batch
#define KS     12      // 192 / 16
#define CSPLIT 16      // cand-space splits (phase 1)
#define NITER  (NT32 / CSPLIT)   // 16
#define NCANDP 256     // packed candidates per query (16 cs * 2 h * 8)
#define P2ROWS 4       // phase-2 rows per block (1 per wave)
#define NSEL   12      // candidates exactly re-ranked per row

typedef __attribute__((ext_vector_type(8)))  short  bf16x8;
typedef __attribute__((ext_vector_type(8)))  unsigned short u16x8;
typedef __attribute__((ext_vector_type(16))) float  f32x16;

static __device__ __forceinline__ unsigned short f2bf(float f) {
    unsigned u = __float_as_uint(f);
    u += 0x7fffu + ((u >> 16) & 1u);          // round-to-nearest-even
    return (unsigned short)(u >> 16);
}
static __device__ __forceinline__ bf16x8 negbf(bf16x8 v) {
    bf16x8 r;
    #pragma unroll
    for (int e = 0; e < 8; ++e) r[e] = (short)(v[e] ^ (short)0x8000);
    return r;
}
static __device__ __forceinline__ unsigned umax2(unsigned a, unsigned b) {
    return a > b ? a : b;
}
static __device__ __forceinline__ unsigned umin2(unsigned a, unsigned b) {
    return a < b ? a : b;
}

// ---------------------------------------------------------------------------
// Kernel A: norms + layouts (unchanged — passing since R13).
//  pk [B][tile32(256)][ks(12)][lane(64)*8] bf16
//     element: point = tile32*32 + (lane&31), k = ks*16 + (lane>>5)*8 + e
//  x_rm [B][N][C] f32 raw; rdnd/ssd f64 per point.
// ---------------------------------------------------------------------------
__global__ __launch_bounds__(256) void knn_normalize(
    const float* __restrict__ x,
    unsigned short* __restrict__ pk, float* __restrict__ x_rm,
    double* __restrict__ rdnd, double* __restrict__ ssd)
{
    __shared__ float  tile[CH][NT + 1];
    __shared__ double rdn_sh[NT];

    const int b   = blockIdx.x >> 7;
    const int rb  = blockIdx.x & 127;
    const int n0  = rb << 6;
    const int tid = threadIdx.x;
    const float* xb = x + (size_t)b * CH * NPTS;

    #pragma unroll
    for (int i = 0; i < (CH * NT) / 256; ++i) {
        int flat = tid + i * 256;
        int c = flat >> 6, j = flat & 63;
        tile[c][j] = xb[(size_t)c * NPTS + n0 + j];
    }
    __syncthreads();

    // 4 threads per point: quarter q covers dims q*48..q*48+47
    {
        const int j = tid >> 2, q = tid & 3;
        double ss = 0.0;
        #pragma unroll 8
        for (int c = 0; c < 48; ++c) {
            double v = (double)tile[q * 48 + c][j];
            ss = fma(v, v, ss);
        }
        ss += __shfl_xor(ss, 1, 64);
        ss += __shfl_xor(ss, 2, 64);
        if (q == 0) {
            double dn = sqrt(ss);
            if (dn < 1e-12) dn = 1e-12;
            double rdn = 1.0 / dn;
            rdn_sh[j] = rdn;
            rdnd[b * NPTS + n0 + j] = rdn;
            ssd [b * NPTS + n0 + j] = ss;
        }
    }
    __syncthreads();

    // packed MFMA-frag bf16 (2 tile32s * 12 ksteps = 24 frags/block)
    #pragma unroll
    for (int i = 0; i < 6; ++i) {
        int pid  = tid + i * 256;
        int frag = pid >> 6;              // 0..23
        int lane = pid & 63;
        int tl   = frag / KS;             // 0..1
        int ks   = frag - tl * KS;        // 0..11
        int rl   = (tl << 5) + (lane & 31);          // local point 0..63
        int kb   = (ks << 4) + ((lane >> 5) << 3);   // k base
        double rdn = rdn_sh[rl];
        u16x8 hv;
        #pragma unroll
        for (int e = 0; e < 8; ++e) {
            float v = (float)((double)tile[kb + e][rl] * rdn);
            hv[e] = f2bf(v);
        }
        size_t base = ((size_t)((b * NT32 + (rb << 1) + tl) * KS + ks)) * 512
                      + ((size_t)lane << 3);
        *(u16x8*)(pk + base) = hv;
    }

    #pragma unroll
    for (int i = 0; i < (CH * NT) / 256; ++i) {
        int flat = tid + i * 256;
        int j = flat / CH, c = flat - j * CH;
        x_rm[(size_t)(b * NPTS + n0 + j) * CH + c] = tile[c][j];
    }
}

// ---------------------------------------------------------------------------
// Phase 1 v14: R16 structure (no-LDS global->reg stream, sorted-ladder,
// lane owns 1 query + 1 depth-8 list) with SPLIT ACCUMULATORS: even ks ->
// acc0 (init 4), odd ks -> acc1 (init 0). Halves the MFMA dependency chain
// (12 -> 6 deep); pack uses acc0[r]+acc1[r]. waves_per_eu(3,3) fits the
// extra 16 AGPRs (measured occupancy was ~2.8/SIMD, so no TLP loss).
// ---------------------------------------------------------------------------
__global__ __attribute__((amdgpu_flat_work_group_size(256, 256),
                          amdgpu_waves_per_eu(3, 3)))
void knn_phase1(
    const unsigned short* __restrict__ pk,
    unsigned* __restrict__ cand_p)
{
    const int bid  = blockIdx.x;          // 2048
    const int b    = bid >> 10;
    const int r10  = bid & 1023;
    const int qb   = r10 >> 4;            // query block 0..63 (128 queries)
    const int cs   = r10 & 15;            // cand split 0..15 (512 cands)
    const int tid  = threadIdx.x;
    const int wave = tid >> 6;            // 0..3
    const int lane = tid & 63;
    const unsigned short* pkb = pk + (size_t)b * (NT32 * KS * 512);

    // query fragments (B operand), negated for acc = 4 - inner
    const int qt = qb * 4 + wave;         // query tile32 0..255
    bf16x8 qf[KS];
    #pragma unroll
    for (int ks = 0; ks < KS; ++ks) {
        const unsigned short* p = pkb + ((size_t)(qt * KS + ks)) * 512 + (lane << 3);
        qf[ks] = negbf(*(const bf16x8*)p);
    }
    #pragma unroll
    for (int ks = 0; ks < KS; ++ks)
        asm volatile("" : "+a"(qf[ks]));   // MFMA-only operand: AGPR class

    // sorted-ascending list; sentinels above all real keys (real < 0x40D00000)
    unsigned lst[TLIST];
    #pragma unroll
    for (int t = 0; t < TLIST; ++t) lst[t] = 0xFFFFFF00u | t;

    const unsigned short* gbase = pkb + (size_t)(cs * NITER) * (KS * 512) + (lane << 3);

    for (int it = 0; it < NITER; ++it) {
        const unsigned short* gt = gbase + (size_t)it * (KS * 512);

        f32x16 acc0, acc1;
        #pragma unroll
        for (int r = 0; r < 16; ++r) { acc0[r] = 4.f; acc1[r] = 0.f; }

        // interleaved even/odd ks -> two independent MFMA chains (6 deep)
        #pragma unroll
        for (int ks = 0; ks < KS; ks += 2) {
            bf16x8 cf0 = *(const bf16x8*)(gt + (ks << 9));
            bf16x8 cf1 = *(const bf16x8*)(gt + ((ks + 1) << 9));
            acc0 = __builtin_amdgcn_mfma_f32_32x32x16_bf16(cf0, qf[ks],     acc0, 0, 0, 0);
            acc1 = __builtin_amdgcn_mfma_f32_32x32x16_bf16(cf1, qf[ks + 1], acc1, 0, 0, 0);
        }

        // sorted-ladder selection: key = 4 - inner (positive -> uint order)
        // packed = (bits & ~0xFF) | (it<<4) | reg ; payload makes keys unique
        const unsigned pb = (unsigned)(it << 4);
        #pragma unroll
        for (int r = 0; r < 16; ++r) {
            unsigned hi = (__float_as_uint(acc0[r] + acc1[r]) & 0xFFFFFF00u)
                          | pb | (unsigned)r;
            #pragma unroll
            for (int t = 0; t < TLIST; ++t) {
                unsigned lo = umin2(lst[t], hi);
                hi = umax2(lst[t], hi);
                lst[t] = lo;
            }
        }
        // keep list in arch VGPRs at the loop back-edge
        asm volatile("" : "+v"(lst[0]), "+v"(lst[1]), "+v"(lst[2]), "+v"(lst[3]),
                          "+v"(lst[4]), "+v"(lst[5]), "+v"(lst[6]), "+v"(lst[7]));
    }

    // write: [B*N query][cs(16)][h(2)][8]  (list is sorted ascending)
    const int query = (qt << 5) + (lane & 31);
    const int h     = lane >> 5;
    unsigned* dst = cand_p + ((size_t)(b * NPTS + query) << 8) + (cs << 4) + (h << 3);
    uint4 w0 = make_uint4(lst[0], lst[1], lst[2], lst[3]);
    uint4 w1 = make_uint4(lst[4], lst[5], lst[6], lst[7]);
    *(uint4*)dst       = w0;
    *(uint4*)(dst + 4) = w1;
}

// ---------------------------------------------------------------------------
// Phase 2: 1 query per wave, 4 per block, 4096 blocks. NSEL=12.
//  (a) per-lane 4 packed cands (uint4), sort4, 12-round wave-min extraction
//  (b) f64 re-rank (12 cands): lane=(cand,quarter), float4 gathers, 2-shfl
//  (c) PARALLEL rank-of-12: each lane counts lex-smaller keys, writes
//      out[rank] directly (replaces the 540-instr serial lane-0 scan)
// ---------------------------------------------------------------------------
__global__ __launch_bounds__(256) void knn_phase2(
    const float* __restrict__ x_rm,
    const double* __restrict__ rdnd, const double* __restrict__ ssd,
    const unsigned* __restrict__ cand_p,
    int* __restrict__ out)
{
    __shared__ double xc[P2ROWS][CH];     // 6144 B
    __shared__ int    sel[P2ROWS][16];
    __shared__ double dks[P2ROWS][16];

    const int bi   = blockIdx.x;          // 4096
    const int b    = bi >> 11;
    const int r0   = (bi & 2047) << 2;
    const int tid  = threadIdx.x;
    const int wave = tid >> 6;
    const int lane = tid & 63;
    const int bN   = b * NPTS;

    for (int i = tid; i < P2ROWS * CH; i += 256) {
        int r = i / CH, c = i - r * CH;
        xc[r][c] = (double)x_rm[(size_t)(bN + r0 + r) * CH + c] * rdnd[bN + r0 + r];
    }
    __syncthreads();

    const int row = r0 + wave;

    // (a) lane's 4 slots: flat f = lane*4+u; cs = f>>4, h = (f>>3)&1, t = f&7
    unsigned long long qq[4];
    {
        uint4 pv = *(const uint4*)(cand_p + ((size_t)(bN + row) << 8) + (lane << 2));
        unsigned pk4[4] = {pv.x, pv.y, pv.z, pv.w};
        #pragma unroll
        for (int u = 0; u < 4; ++u) {
            int f = (lane << 2) + u;
            int cs = f >> 4, h = (f >> 3) & 1;
            unsigned pkv = pk4[u];
            int r = (int)(pkv & 15u), ct = (int)((pkv >> 4) & 15u);
            int rowc = (r & 3) + ((r >> 2) << 3) + (h << 2);
            int col  = (cs << 9) + (ct << 5) + rowc;
            qq[u] = ((unsigned long long)pkv << 32) | (unsigned)col;
        }
        // sort4 ascending (5 CE)
        unsigned long long t;
        #define CE(a, b) if (qq[b] < qq[a]) { t = qq[a]; qq[a] = qq[b]; qq[b] = t; }
        CE(0,1) CE(2,3) CE(0,2) CE(1,3) CE(1,2)
        #undef CE
    }

    // NSEL extraction rounds of wave-wide u64 min; lane r captures round r
    unsigned long long my_sel = 0;
    #pragma unroll
    for (int round = 0; round < NSEL; ++round) {
        unsigned long long m = qq[0];
        #pragma unroll
        for (int off = 1; off < 64; off <<= 1) {
            unsigned long long o = __shfl_xor(m, off, 64);
            m = (o < m) ? o : m;
        }
        if (qq[0] == m) {                 // exactly one lane (u64 unique via col)
            qq[0] = qq[1]; qq[1] = qq[2]; qq[2] = qq[3];
            qq[3] = 0xFFFFFFFFFFFFFFFFull;
        }
        if (lane == round) my_sel = m;
    }
    if (lane < NSEL) sel[wave][lane] = (int)((unsigned)my_sel & 0x3FFFu);
    __builtin_amdgcn_wave_barrier();

    // (b) exact f64 keys: lane = (cand c, quarter qd), c < NSEL active
    {
        const int c = lane & 15, qd = lane >> 4;
        if (c < NSEL) {
            const int m = sel[wave][c];
            const double rdm = rdnd[bN + m];
            const float* xr = x_rm + (size_t)(bN + m) * CH + qd * 48;
            const double* xcp = &xc[wave][qd * 48];
            double s0 = 0.0, s1 = 0.0, s2 = 0.0, s3 = 0.0;
            #pragma unroll
            for (int j = 0; j < 12; ++j) {
                float4 v = *(const float4*)(xr + (j << 2));
                s0 = fma((double)v.x * rdm, xcp[(j << 2) + 0], s0);
                s1 = fma((double)v.y * rdm, xcp[(j << 2) + 1], s1);
                s2 = fma((double)v.z * rdm, xcp[(j << 2) + 2], s2);
                s3 = fma((double)v.w * rdm, xcp[(j << 2) + 3], s3);
            }
            double dot = (s0 + s1) + (s2 + s3);
            dot += __shfl_xor(dot, 16, 64);
            dot += __shfl_xor(dot, 32, 64);
            if (qd == 0) dks[wave][c] = fma(-2.0, dot, ssd[bN + m] * rdm * rdm);
        } else {
            double dot = 0.0;             // keep shuffles wave-uniform
            dot += __shfl_xor(dot, 16, 64);
            dot += __shfl_xor(dot, 32, 64);
        }
    }
    __builtin_amdgcn_wave_barrier();

    // (c) parallel rank: lane c < NSEL counts lex-smaller keys; rank < 9 wins
    if (lane < NSEL) {
        const double dm = dks[wave][lane];
        const int    sm = sel[wave][lane];
        int cnt = 0;
        #pragma unroll
        for (int s = 0; s < NSEL; ++s) {
            double d = dks[wave][s]; int m = sel[wave][s];
            cnt += (d < dm || (d == dm && m < sm)) ? 1 : 0;
        }
        if (cnt < KNN) {
            const int n = row;
            out[(size_t)(bN + n) * KNN + cnt] = sm;
            out[(size_t)BATCH * NPTS * KNN + (size_t)(bN + n) * KNN + cnt] = n;
        }
    }
}

// ---------------------------------------------------------------------------
extern "C" void kernel_launch(void* const* d_in, const int* in_sizes, int n_in,
                              void* d_out, int out_size, void* d_ws, size_t ws_size,
                              hipStream_t stream)
{
    const float* x = (const float*)d_in[0];
    int* out = (int*)d_out;

    char* ws = (char*)d_ws;
    const size_t sz_pk  = (size_t)BATCH * NT32 * KS * 512 * sizeof(unsigned short); // 6.29 MB
    const size_t sz_xrm = (size_t)BATCH * NPTS * CH * sizeof(float);                // 12.58 MB
    const size_t sz_rdn = (size_t)BATCH * NPTS * sizeof(double);
    const size_t sz_ss  = sz_rdn;

    unsigned short* pk = (unsigned short*)(ws);
    float*  x_rm   = (float*) (ws + sz_pk);
    double* rdnd   = (double*)(ws + sz_pk + sz_xrm);
    double* ssd    = (double*)(ws + sz_pk + sz_xrm + sz_rdn);
    unsigned* cand_p = (unsigned*)(ws + sz_pk + sz_xrm + sz_rdn + sz_ss);           // 16.8 MB

    knn_normalize<<<BATCH * (NPTS / NT), 256, 0, stream>>>(x, pk, x_rm, rdnd, ssd);
    knn_phase1  <<<BATCH * 64 * CSPLIT, 256, 0, stream>>>(pk, cand_p);
    knn_phase2  <<<BATCH * (NPTS / P2ROWS), 256, 0, stream>>>(x_rm, rdnd, ssd, cand_p, out);
}

// Round 18
// 149.769 us; speedup vs baseline: 1.3398x; 1.0731x over previous
//
#include <hip/hip_runtime.h>
#include <math.h>

#define BATCH 2
#define CH    192
#define NPTS  8192
#define KNN   9

#define NT     64      // rows per normalize block
#define TLIST  8       // per-lane candidate list depth
#define NT32   256     // 32-wide point tiles per batch
#define KS     12      // 192 / 16
#define CSPLIT 16      // cand-space splits (phase 1)
#define NITER  (NT32 / CSPLIT)   // 16
#define NCANDP 256     // packed candidates per query (16 cs * 2 h * 8)
#define P2ROWS 4       // phase-2 rows per block (1 per wave)
#define NSEL   12      // candidates exactly re-ranked per row

typedef __attribute__((ext_vector_type(8)))  short  bf16x8;
typedef __attribute__((ext_vector_type(8)))  unsigned short u16x8;
typedef __attribute__((ext_vector_type(16))) float  f32x16;

static __device__ __forceinline__ unsigned short f2bf(float f) {
    unsigned u = __float_as_uint(f);
    u += 0x7fffu + ((u >> 16) & 1u);          // round-to-nearest-even
    return (unsigned short)(u >> 16);
}
static __device__ __forceinline__ bf16x8 negbf(bf16x8 v) {
    bf16x8 r;
    #pragma unroll
    for (int e = 0; e < 8; ++e) r[e] = (short)(v[e] ^ (short)0x8000);
    return r;
}
static __device__ __forceinline__ unsigned umax2(unsigned a, unsigned b) {
    return a > b ? a : b;
}
static __device__ __forceinline__ unsigned umin2(unsigned a, unsigned b) {
    return a < b ? a : b;
}

// ---------------------------------------------------------------------------
// Kernel A: norms + layouts (unchanged — passing since R13).
//  pk [B][tile32(256)][ks(12)][lane(64)*8] bf16
//     element: point = tile32*32 + (lane&31), k = ks*16 + (lane>>5)*8 + e
//  x_rm [B][N][C] f32 raw; rdnd/ssd f64 per point.
// ---------------------------------------------------------------------------
__global__ __launch_bounds__(256) void knn_normalize(
    const float* __restrict__ x,
    unsigned short* __restrict__ pk, float* __restrict__ x_rm,
    double* __restrict__ rdnd, double* __restrict__ ssd)
{
    __shared__ float  tile[CH][NT + 1];
    __shared__ double rdn_sh[NT];

    const int b   = blockIdx.x >> 7;
    const int rb  = blockIdx.x & 127;
    const int n0  = rb << 6;
    const int tid = threadIdx.x;
    const float* xb = x + (size_t)b * CH * NPTS;

    #pragma unroll
    for (int i = 0; i < (CH * NT) / 256; ++i) {
        int flat = tid + i * 256;
        int c = flat >> 6, j = flat & 63;
        tile[c][j] = xb[(size_t)c * NPTS + n0 + j];
    }
    __syncthreads();

    // 4 threads per point: quarter q covers dims q*48..q*48+47
    {
        const int j = tid >> 2, q = tid & 3;
        double ss = 0.0;
        #pragma unroll 8
        for (int c = 0; c < 48; ++c) {
            double v = (double)tile[q * 48 + c][j];
            ss = fma(v, v, ss);
        }
        ss += __shfl_xor(ss, 1, 64);
        ss += __shfl_xor(ss, 2, 64);
        if (q == 0) {
            double dn = sqrt(ss);
            if (dn < 1e-12) dn = 1e-12;
            double rdn = 1.0 / dn;
            rdn_sh[j] = rdn;
            rdnd[b * NPTS + n0 + j] = rdn;
            ssd [b * NPTS + n0 + j] = ss;
        }
    }
    __syncthreads();

    // packed MFMA-frag bf16 (2 tile32s * 12 ksteps = 24 frags/block)
    #pragma unroll
    for (int i = 0; i < 6; ++i) {
        int pid  = tid + i * 256;
        int frag = pid >> 6;              // 0..23
        int lane = pid & 63;
        int tl   = frag / KS;             // 0..1
        int ks   = frag - tl * KS;        // 0..11
        int rl   = (tl << 5) + (lane & 31);          // local point 0..63
        int kb   = (ks << 4) + ((lane >> 5) << 3);   // k base
        double rdn = rdn_sh[rl];
        u16x8 hv;
        #pragma unroll
        for (int e = 0; e < 8; ++e) {
            float v = (float)((double)tile[kb + e][rl] * rdn);
            hv[e] = f2bf(v);
        }
        size_t base = ((size_t)((b * NT32 + (rb << 1) + tl) * KS + ks)) * 512
                      + ((size_t)lane << 3);
        *(u16x8*)(pk + base) = hv;
    }

    #pragma unroll
    for (int i = 0; i < (CH * NT) / 256; ++i) {
        int flat = tid + i * 256;
        int j = flat / CH, c = flat - j * CH;
        x_rm[(size_t)(b * NPTS + n0 + j) * CH + c] = tile[c][j];
    }
}

// ---------------------------------------------------------------------------
// Phase 1 (R16 v13 exact — best measured: ~97 µs, occupancy 35%):
// NO LDS, NO barriers. Cand fragments stream global->reg (pk L2-resident;
// L1 serves re-reads; 16 waves/CU TLP hides latency). Sorted-ladder
// selection; lane owns 1 query + 1 depth-8 list. waves_per_eu(4,4).
// ---------------------------------------------------------------------------
__global__ __attribute__((amdgpu_flat_work_group_size(256, 256),
                          amdgpu_waves_per_eu(4, 4)))
void knn_phase1(
    const unsigned short* __restrict__ pk,
    unsigned* __restrict__ cand_p)
{
    const int bid  = blockIdx.x;          // 2048
    const int b    = bid >> 10;
    const int r10  = bid & 1023;
    const int qb   = r10 >> 4;            // query block 0..63 (128 queries)
    const int cs   = r10 & 15;            // cand split 0..15 (512 cands)
    const int tid  = threadIdx.x;
    const int wave = tid >> 6;            // 0..3
    const int lane = tid & 63;
    const unsigned short* pkb = pk + (size_t)b * (NT32 * KS * 512);

    // query fragments (B operand), negated for acc = 4 - inner
    const int qt = qb * 4 + wave;         // query tile32 0..255
    bf16x8 qf[KS];
    #pragma unroll
    for (int ks = 0; ks < KS; ++ks) {
        const unsigned short* p = pkb + ((size_t)(qt * KS + ks)) * 512 + (lane << 3);
        qf[ks] = negbf(*(const bf16x8*)p);
    }
    #pragma unroll
    for (int ks = 0; ks < KS; ++ks)
        asm volatile("" : "+a"(qf[ks]));   // MFMA-only operand: AGPR class

    // sorted-ascending list; sentinels above all real keys (real < 0x40D00000)
    unsigned lst[TLIST];
    #pragma unroll
    for (int t = 0; t < TLIST; ++t) lst[t] = 0xFFFFFF00u | t;

    const unsigned short* gbase = pkb + (size_t)(cs * NITER) * (KS * 512) + (lane << 3);

    for (int it = 0; it < NITER; ++it) {
        const unsigned short* gt = gbase + (size_t)it * (KS * 512);

        f32x16 acc;
        #pragma unroll
        for (int r = 0; r < 16; ++r) acc[r] = 4.f;

        #pragma unroll
        for (int ks = 0; ks < KS; ++ks) {
            bf16x8 cf = *(const bf16x8*)(gt + (ks << 9));
            acc = __builtin_amdgcn_mfma_f32_32x32x16_bf16(cf, qf[ks], acc, 0, 0, 0);
        }

        // sorted-ladder selection: key = 4 - inner (positive -> uint order)
        // packed = (bits & ~0xFF) | (it<<4) | reg ; payload makes keys unique
        const unsigned pb = (unsigned)(it << 4);
        #pragma unroll
        for (int r = 0; r < 16; ++r) {
            unsigned hi = (__float_as_uint(acc[r]) & 0xFFFFFF00u) | pb | (unsigned)r;
            #pragma unroll
            for (int t = 0; t < TLIST; ++t) {
                unsigned lo = umin2(lst[t], hi);
                hi = umax2(lst[t], hi);
                lst[t] = lo;
            }
        }
        // keep list in arch VGPRs at the loop back-edge
        asm volatile("" : "+v"(lst[0]), "+v"(lst[1]), "+v"(lst[2]), "+v"(lst[3]),
                          "+v"(lst[4]), "+v"(lst[5]), "+v"(lst[6]), "+v"(lst[7]));
    }

    // write: [B*N query][cs(16)][h(2)][8]  (list is sorted ascending)
    const int query = (qt << 5) + (lane & 31);
    const int h     = lane >> 5;
    unsigned* dst = cand_p + ((size_t)(b * NPTS + query) << 8) + (cs << 4) + (h << 3);
    uint4 w0 = make_uint4(lst[0], lst[1], lst[2], lst[3]);
    uint4 w1 = make_uint4(lst[4], lst[5], lst[6], lst[7]);
    *(uint4*)dst       = w0;
    *(uint4*)(dst + 4) = w1;
}

// ---------------------------------------------------------------------------
// Phase 2 (R17 exact — parallel rank, NSEL=12): 1 query per wave.
//  (a) per-lane 4 packed cands (uint4), sort4, 12-round wave-min extraction
//  (b) f64 re-rank (12 cands): lane=(cand,quarter), float4 gathers, 2-shfl
//  (c) parallel rank-of-12: each lane counts lex-smaller keys, writes
//      out[rank] directly
// ---------------------------------------------------------------------------
__global__ __launch_bounds__(256) void knn_phase2(
    const float* __restrict__ x_rm,
    const double* __restrict__ rdnd, const double* __restrict__ ssd,
    const unsigned* __restrict__ cand_p,
    int* __restrict__ out)
{
    __shared__ double xc[P2ROWS][CH];     // 6144 B
    __shared__ int    sel[P2ROWS][16];
    __shared__ double dks[P2ROWS][16];

    const int bi   = blockIdx.x;          // 4096
    const int b    = bi >> 11;
    const int r0   = (bi & 2047) << 2;
    const int tid  = threadIdx.x;
    const int wave = tid >> 6;
    const int lane = tid & 63;
    const int bN   = b * NPTS;

    for (int i = tid; i < P2ROWS * CH; i += 256) {
        int r = i / CH, c = i - r * CH;
        xc[r][c] = (double)x_rm[(size_t)(bN + r0 + r) * CH + c] * rdnd[bN + r0 + r];
    }
    __syncthreads();

    const int row = r0 + wave;

    // (a) lane's 4 slots: flat f = lane*4+u; cs = f>>4, h = (f>>3)&1, t = f&7
    unsigned long long qq[4];
    {
        uint4 pv = *(const uint4*)(cand_p + ((size_t)(bN + row) << 8) + (lane << 2));
        unsigned pk4[4] = {pv.x, pv.y, pv.z, pv.w};
        #pragma unroll
        for (int u = 0; u < 4; ++u) {
            int f = (lane << 2) + u;
            int cs = f >> 4, h = (f >> 3) & 1;
            unsigned pkv = pk4[u];
            int r = (int)(pkv & 15u), ct = (int)((pkv >> 4) & 15u);
            int rowc = (r & 3) + ((r >> 2) << 3) + (h << 2);
            int col  = (cs << 9) + (ct << 5) + rowc;
            qq[u] = ((unsigned long long)pkv << 32) | (unsigned)col;
        }
        // sort4 ascending (5 CE)
        unsigned long long t;
        #define CE(a, b) if (qq[b] < qq[a]) { t = qq[a]; qq[a] = qq[b]; qq[b] = t; }
        CE(0,1) CE(2,3) CE(0,2) CE(1,3) CE(1,2)
        #undef CE
    }

    // NSEL extraction rounds of wave-wide u64 min; lane r captures round r
    unsigned long long my_sel = 0;
    #pragma unroll
    for (int round = 0; round < NSEL; ++round) {
        unsigned long long m = qq[0];
        #pragma unroll
        for (int off = 1; off < 64; off <<= 1) {
            unsigned long long o = __shfl_xor(m, off, 64);
            m = (o < m) ? o : m;
        }
        if (qq[0] == m) {                 // exactly one lane (u64 unique via col)
            qq[0] = qq[1]; qq[1] = qq[2]; qq[2] = qq[3];
            qq[3] = 0xFFFFFFFFFFFFFFFFull;
        }
        if (lane == round) my_sel = m;
    }
    if (lane < NSEL) sel[wave][lane] = (int)((unsigned)my_sel & 0x3FFFu);
    __builtin_amdgcn_wave_barrier();

    // (b) exact f64 keys: lane = (cand c, quarter qd), c < NSEL active
    {
        const int c = lane & 15, qd = lane >> 4;
        if (c < NSEL) {
            const int m = sel[wave][c];
            const double rdm = rdnd[bN + m];
            const float* xr = x_rm + (size_t)(bN + m) * CH + qd * 48;
            const double* xcp = &xc[wave][qd * 48];
            double s0 = 0.0, s1 = 0.0, s2 = 0.0, s3 = 0.0;
            #pragma unroll
            for (int j = 0; j < 12; ++j) {
                float4 v = *(const float4*)(xr + (j << 2));
                s0 = fma((double)v.x * rdm, xcp[(j << 2) + 0], s0);
                s1 = fma((double)v.y * rdm, xcp[(j << 2) + 1], s1);
                s2 = fma((double)v.z * rdm, xcp[(j << 2) + 2], s2);
                s3 = fma((double)v.w * rdm, xcp[(j << 2) + 3], s3);
            }
            double dot = (s0 + s1) + (s2 + s3);
            dot += __shfl_xor(dot, 16, 64);
            dot += __shfl_xor(dot, 32, 64);
            if (qd == 0) dks[wave][c] = fma(-2.0, dot, ssd[bN + m] * rdm * rdm);
        } else {
            double dot = 0.0;             // keep shuffles wave-uniform
            dot += __shfl_xor(dot, 16, 64);
            dot += __shfl_xor(dot, 32, 64);
        }
    }
    __builtin_amdgcn_wave_barrier();

    // (c) parallel rank: lane c < NSEL counts lex-smaller keys; rank < 9 wins
    if (lane < NSEL) {
        const double dm = dks[wave][lane];
        const int    sm = sel[wave][lane];
        int cnt = 0;
        #pragma unroll
        for (int s = 0; s < NSEL; ++s) {
            double d = dks[wave][s]; int m = sel[wave][s];
            cnt += (d < dm || (d == dm && m < sm)) ? 1 : 0;
        }
        if (cnt < KNN) {
            const int n = row;
            out[(size_t)(bN + n) * KNN + cnt] = sm;
            out[(size_t)BATCH * NPTS * KNN + (size_t)(bN + n) * KNN + cnt] = n;
        }
    }
}

// ---------------------------------------------------------------------------
extern "C" void kernel_launch(void* const* d_in, const int* in_sizes, int n_in,
                              void* d_out, int out_size, void* d_ws, size_t ws_size,
                              hipStream_t stream)
{
    const float* x = (const float*)d_in[0];
    int* out = (int*)d_out;

    char* ws = (char*)d_ws;
    const size_t sz_pk  = (size_t)BATCH * NT32 * KS * 512 * sizeof(unsigned short); // 6.29 MB
    const size_t sz_xrm = (size_t)BATCH * NPTS * CH * sizeof(float);                // 12.58 MB
    const size_t sz_rdn = (size_t)BATCH * NPTS * sizeof(double);
    const size_t sz_ss  = sz_rdn;

    unsigned short* pk = (unsigned short*)(ws);
    float*  x_rm   = (float*) (ws + sz_pk);
    double* rdnd   = (double*)(ws + sz_pk + sz_xrm);
    double* ssd    = (double*)(ws + sz_pk + sz_xrm + sz_rdn);
    unsigned* cand_p = (unsigned*)(ws + sz_pk + sz_xrm + sz_rdn + sz_ss);           // 16.8 MB

    knn_normalize<<<BATCH * (NPTS / NT), 256, 0, stream>>>(x, pk, x_rm, rdnd, ssd);
    knn_phase1  <<<BATCH * 64 * CSPLIT, 256, 0, stream>>>(pk, cand_p);
    knn_phase2  <<<BATCH * (NPTS / P2ROWS), 256, 0, stream>>>(x_rm, rdnd, ssd, cand_p, out);
}